// Round 8
// baseline (118.340 us; speedup 1.0000x reference)
//
#include <hip/hip_runtime.h>

#define Bn 32
#define Cn 64
#define Hn 56
#define Wn 56
#define REPN 50
#define NKn 17
#define HWn (Hn*Wn)           // 3136
#define NSTATf 100352.0f      // B*H*W
#define EPSf 1e-5f

// ---- fused-kernel ws layout (zeroed by hipMemsetAsync each iteration) ----
#define GCNT_OFF 0            // unsigned [r(50)][32] (128B stride) = 1600 ints
#define GSUM_OFF 1600         // float [r(50)][8] = 400 floats (6 used)
#define INIT_BYTES 8000       // bytes 0..8000 zeroed
// ---- fallback-chain scratch (disjoint) ----
#define PART_OFF 4096         // [stat(6)][r(50)][b(32)] = 9600

#define SEGH 7
#define NTASK 112             // 8 row-segments * 14 quad-cols
#define GRID_FUSED 1024       // 4 blocks/CU -> co-resident (LDS 38.2KB/block)
#define PLW (HWn/2)           // 1568 u32 per bf16 plane

// ------------------------------------------------- bf16 pack/unpack (RNE)
__device__ __forceinline__ unsigned bfpack2(float a, float b)
{
    unsigned ua = __float_as_uint(a);
    unsigned ub = __float_as_uint(b);
    ua += 0x7FFFu + ((ua >> 16) & 1u);
    ub += 0x7FFFu + ((ub >> 16) & 1u);
    return (ua >> 16) | (ub & 0xFFFF0000u);
}
__device__ __forceinline__ float bflo(unsigned u){ return __uint_as_float(u << 16); }
__device__ __forceinline__ float bfhi(unsigned u){ return __uint_as_float(u & 0xFFFF0000u); }

// ---------------------------------------------------------------- weff in LDS
// swk layout t-major: swk[t*9+ij]; t: 0..2 Mh shifts, 3..5 Mv shifts, 6 Mid.
__device__ __forceinline__ void block_weff(int r, int tid,
        const float* __restrict__ w0, const float* __restrict__ w1,
        const int* __restrict__ Mh, const int* __restrict__ Mv,
        const int* __restrict__ Mid, float* __restrict__ swk)
{
    if (tid >= 0 && tid < 63) {
        int t = tid / 9, ij = tid - t*9;
        const int* M = (t < 3) ? (Mh + (t*REPN + r)*NKn)
                     : (t < 6) ? (Mv + ((t-3)*REPN + r)*NKn)
                               : (Mid + r*NKn);
        float acc = 0.f;
        #pragma unroll
        for (int k = 0; k < NKn; ++k)
            acc += (float)M[k] * (w0[(r*NKn + k)*9 + ij] + w1[(r*NKn + k)*9 + ij]);
        swk[t*9 + ij] = acc;
    }
}

// Load input row `row` of channel ch as window X[0..7] = cols 4q-3..4q+4
// (zeros outside [0,56)). Also c55 = input[row][55] for q==0 lanes.
__device__ __forceinline__ void load_row8c(const float* __restrict__ ch, int row, int q,
                                           float* __restrict__ X, float& c55)
{
    bool rv = (row >= 0) && (row < Hn);
    int rc = rv ? row : 0;
    const float* rp = ch + rc*Wn;
    float4 c0 = *(const float4*)(rp + (q ? 4*q - 4 : 0));   // cols 4q-4..4q-1
    float4 c1 = *(const float4*)(rp + 4*q);                 // cols 4q..4q+3
    int ox = (4*q + 4 <= 55) ? 4*q + 4 : 55;                // clamp in-row
    float cx = rp[ox];
    float mr = rv ? 1.f : 0.f;
    float m0 = (rv && q > 0)  ? 1.f : 0.f;
    float mx = (rv && q < 13) ? 1.f : 0.f;
    X[0]=c0.y*m0; X[1]=c0.z*m0; X[2]=c0.w*m0;
    X[3]=c1.x*mr; X[4]=c1.y*mr; X[5]=c1.z*mr; X[6]=c1.w*mr;
    X[7]=cx*mx;
    c55 = (q == 0) ? rp[55]*mr : 0.f;
}

// -------------------------------------------- 3-accumulator walk (stats pass)
// 6-row rolling window, 2-row prefetch lookahead (R6-proven).
template <typename F>
__device__ __forceinline__ void conv_walk3(const float* __restrict__ ch,
        const float (&wk)[63], int tid, F emit)
{
    if (tid >= NTASK) return;
    int seg = tid / 14;
    int q   = tid - seg*14;
    int h0  = seg * SEGH;
    bool top = (seg == 0);

    float W[6][8], C[6], T[8];
    {
        float dummy;
        if (top) load_row8c(ch, 55, q, T, dummy);
    }
    #pragma unroll
    for (int k = 0; k < 6; ++k)
        load_row8c(ch, h0 - 3 + k, q, W[k], C[k]);

    #pragma unroll
    for (int s = 0; s < SEGH; ++s) {
        int h = h0 + s;
        float Wn8[8], Cn1;
        load_row8c(ch, h + 3, q, Wn8, Cn1);   // prefetch 2 rows ahead

        float l1[4], l2[4], sm[4];
        #pragma unroll
        for (int p = 0; p < 4; ++p) { l1[p]=0.f; l2[p]=0.f; sm[p]=0.f; }
        #pragma unroll
        for (int i = 0; i < 3; ++i)
            #pragma unroll
            for (int j = 0; j < 3; ++j) {
                int ij = i*3 + j;
                float wh0 = wk[ij],    wh1 = wk[9+ij],  wh2 = wk[18+ij];
                float wv0 = wk[27+ij], wv1 = wk[36+ij], wv2 = wk[45+ij];
                float wid = wk[54+ij];
                #pragma unroll
                for (int p = 0; p < 4; ++p) {
                    float a  = W[2+i][p+2+j];     // pos0
                    l1[p] = fmaf(a, wh0, l1[p]);
                    l2[p] = fmaf(a, wv0, l2[p]);
                    sm[p] = fmaf(a, wid, sm[p]);
                    float bA = W[1+i][p+j];       // posA
                    l1[p] = fmaf(bA, wh1, l1[p]);
                    l2[p] = fmaf(bA, wv2, l2[p]);
                    float bB = W[i][p+1+j];       // posB
                    l1[p] = fmaf(bB, wh2, l1[p]);
                    l2[p] = fmaf(bB, wv1, l2[p]);
                }
            }
        if (q == 0) {   // col wrap, pixel 0: posA j=0 -> t1 (l1), t5 (l2)
            #pragma unroll
            for (int i = 0; i < 3; ++i) {
                l1[0] = fmaf(C[1+i], wk[9+3*i],  l1[0]);
                l2[0] = fmaf(C[1+i], wk[45+3*i], l2[0]);
            }
        }
        if (s == 0 && top) {   // row wrap, h==0: posB i=0 -> t2 (l1), t4 (l2)
            #pragma unroll
            for (int j = 0; j < 3; ++j)
                #pragma unroll
                for (int p = 0; p < 4; ++p) {
                    l1[p] = fmaf(T[p+1+j], wk[18+j], l1[p]);
                    l2[p] = fmaf(T[p+1+j], wk[36+j], l2[p]);
                }
        }
        float res[4] = {W[3][3], W[3][4], W[3][5], W[3][6]};
        emit(h, q, l1, l2, sm, res);

        #pragma unroll
        for (int k = 0; k < 5; ++k) {
            #pragma unroll
            for (int x = 0; x < 8; ++x) W[k][x] = W[k+1][x];
            C[k] = C[k+1];
        }
        #pragma unroll
        for (int x = 0; x < 8; ++x) W[5][x] = Wn8[x];
        C[5] = Cn1;
    }
}

// ------------------------------- single-accumulator walk (fallback pass 2)
__device__ __forceinline__ void conv_walk1(const float* __restrict__ ch,
        const float (&cw0)[9], const float (&cwA)[9], const float (&cwB)[9],
        float Kc, int tid, float* __restrict__ dst)
{
    if (tid >= NTASK) return;
    int seg = tid / 14;
    int q   = tid - seg*14;
    int h0  = seg * SEGH;
    bool top = (seg == 0);

    float W[6][8], C[6], T[8];
    {
        float dummy;
        if (top) load_row8c(ch, 55, q, T, dummy);
    }
    #pragma unroll
    for (int k = 0; k < 6; ++k)
        load_row8c(ch, h0 - 3 + k, q, W[k], C[k]);

    #pragma unroll
    for (int s = 0; s < SEGH; ++s) {
        int h = h0 + s;
        float Wn8[8], Cn1;
        load_row8c(ch, h + 3, q, Wn8, Cn1);

        float acc[4];
        #pragma unroll
        for (int p = 0; p < 4; ++p) acc[p] = 0.f;
        #pragma unroll
        for (int i = 0; i < 3; ++i)
            #pragma unroll
            for (int j = 0; j < 3; ++j) {
                int ij = i*3 + j;
                float w0c = cw0[ij], wAc = cwA[ij], wBc = cwB[ij];
                #pragma unroll
                for (int p = 0; p < 4; ++p) {
                    acc[p] = fmaf(W[2+i][p+2+j], w0c, acc[p]);
                    acc[p] = fmaf(W[1+i][p+j],   wAc, acc[p]);
                    acc[p] = fmaf(W[i][p+1+j],   wBc, acc[p]);
                }
            }
        if (q == 0) {
            #pragma unroll
            for (int i = 0; i < 3; ++i)
                acc[0] = fmaf(C[1+i], cwA[3*i], acc[0]);
        }
        if (s == 0 && top) {
            #pragma unroll
            for (int j = 0; j < 3; ++j)
                #pragma unroll
                for (int p = 0; p < 4; ++p)
                    acc[p] = fmaf(T[p+1+j], cwB[j], acc[p]);
        }
        float4 o;
        o.x = acc[0] - Kc + W[3][3];
        o.y = acc[1] - Kc + W[3][4];
        o.z = acc[2] - Kc + W[3][5];
        o.w = acc[3] - Kc + W[3][6];
        *(float4*)(dst + h*Wn + 4*q) = o;

        #pragma unroll
        for (int k = 0; k < 5; ++k) {
            #pragma unroll
            for (int x = 0; x < 8; ++x) W[k][x] = W[k+1][x];
            C[k] = C[k+1];
        }
        #pragma unroll
        for (int x = 0; x < 8; ++x) W[5][x] = Wn8[x];
        C[5] = Cn1;
    }
}

// ------------------------------------------------ helpers for fused kernel
// stats + plane capture: conv once, accumulate moments AND store l1/l2/sm
// quads as packed bf16 into this task's LDS planes (pl = 3*PLW u32).
__device__ __forceinline__ void stats_and_arrive(const float* __restrict__ ch,
        const float* __restrict__ swk, int r, int tid,
        float* __restrict__ ws, float (*red)[6], unsigned* __restrict__ pl)
{
    float wk[63];
    #pragma unroll
    for (int i = 0; i < 63; ++i) wk[i] = swk[i];

    float s1=0.f,q1=0.f,s2=0.f,q2=0.f,s3=0.f,q3=0.f;
    conv_walk3(ch, wk, tid,
        [&](int h, int q, float* l1, float* l2, float* sm, float* res) {
            (void)res;
            #pragma unroll
            for (int p = 0; p < 4; ++p) {
                s1 += l1[p]; q1 += l1[p]*l1[p];
                s2 += l2[p]; q2 += l2[p]*l2[p];
                s3 += sm[p]; q3 += sm[p]*sm[p];
            }
            int b2 = (h*Wn + 4*q) >> 1;            // u32 index, even
            *(uint2*)&pl[0*PLW + b2] = make_uint2(bfpack2(l1[0],l1[1]), bfpack2(l1[2],l1[3]));
            *(uint2*)&pl[1*PLW + b2] = make_uint2(bfpack2(l2[0],l2[1]), bfpack2(l2[2],l2[3]));
            *(uint2*)&pl[2*PLW + b2] = make_uint2(bfpack2(sm[0],sm[1]), bfpack2(sm[2],sm[3]));
        });
    {
        float vals[6] = {s1,q1,s2,q2,s3,q3};
        int lane = tid & 63, wave = tid >> 6;
        #pragma unroll
        for (int x = 0; x < 6; ++x) {
            float y = vals[x];
            for (int o = 32; o; o >>= 1) y += __shfl_down(y, o, 64);
            if (lane == 0) red[wave][x] = y;
        }
    }
    __syncthreads();
    if (tid < 6) {
        atomicAdd(ws + GSUM_OFF + r*8 + tid, red[0][tid] + red[1][tid]);
        __threadfence();                       // release: sums visible first
    }
    __syncthreads();
    if (tid == 0)
        atomicAdd(((unsigned*)ws) + GCNT_OFF + r*32, 1u);
    __syncthreads();
}

// wait + finalize from LDS planes: no second conv. Per quad: 3 ds_read (8B)
// + one L2-warm residual float4 + 12 FMA.
__device__ __forceinline__ void wait_and_finalize(const float* __restrict__ ch,
        int r, int tid, float* __restrict__ ws, float* __restrict__ sred,
        const unsigned* __restrict__ pl, float* __restrict__ dst)
{
    if (tid == 0) {
        unsigned* gc = ((unsigned*)ws) + GCNT_OFF + r*32;
        while (atomicAdd(gc, 0u) < (unsigned)Bn)
            __builtin_amdgcn_s_sleep(8);
    }
    __syncthreads();                           // acquire for whole block
    if (tid < 6) sred[tid] = atomicAdd(ws + GSUM_OFF + r*8 + tid, 0.f);
    __syncthreads();

    const float inv = 1.0f / NSTATf;
    float m1 = sred[0]*inv, v1 = sred[1]*inv - m1*m1;
    float m2 = sred[2]*inv, v2 = sred[3]*inv - m2*m2;
    float m3 = sred[4]*inv, v3 = sred[5]*inv - m3*m3;
    float r1 = rsqrtf(v1 + EPSf), r2 = rsqrtf(v2 + EPSf), r3 = rsqrtf(v3 + EPSf);
    float Kc = m1*r1 + m2*r2 + m3*r3;

    if (tid >= NTASK) return;
    int seg = tid / 14;
    int q   = tid - seg*14;
    int h0  = seg * SEGH;

    #pragma unroll
    for (int s = 0; s < SEGH; ++s) {
        int bi = (h0 + s)*Wn + 4*q;
        int b2 = bi >> 1;
        float4 res = *(const float4*)(ch + bi);        // L2-warm re-read
        uint2 u1 = *(const uint2*)&pl[0*PLW + b2];
        uint2 u2 = *(const uint2*)&pl[1*PLW + b2];
        uint2 u3 = *(const uint2*)&pl[2*PLW + b2];
        float4 o;
        o.x = bflo(u1.x)*r1 + bflo(u2.x)*r2 + bflo(u3.x)*r3 - Kc + res.x;
        o.y = bfhi(u1.x)*r1 + bfhi(u2.x)*r2 + bfhi(u3.x)*r3 - Kc + res.y;
        o.z = bflo(u1.y)*r1 + bflo(u2.y)*r2 + bflo(u3.y)*r3 - Kc + res.z;
        o.w = bfhi(u1.y)*r1 + bfhi(u2.y)*r2 + bfhi(u3.y)*r3 - Kc + res.w;
        *(float4*)(dst + bi) = o;
    }
}

// --------------------------------------------- fused single kernel (plain)
// 1024 blocks x 128. Block bid = b*32 + pr owns tasks (b, 2pr), (b, 2pr+1).
// REPN=50 even -> pairs homogeneous: pr<25 rep, pr>=25 ghost.
// stats+arrive(A) -> stats+arrive(B) -> wait+fin(A) -> wait+fin(B):
// all arrivals precede all waits within each independent 32-block r-group;
// LDS 38.2KB -> exactly 4 blocks/CU co-resident (gated host-side).
__global__ void __launch_bounds__(128) k_fused(const float* __restrict__ in,
        const float* __restrict__ w0, const float* __restrict__ w1,
        const int* __restrict__ Mh, const int* __restrict__ Mv,
        const int* __restrict__ Mid,
        const int* __restrict__ rep_idx, const int* __restrict__ ghost_idx,
        float* __restrict__ ws, float* __restrict__ out)
{
    int tid = threadIdx.x;
    int bid = blockIdx.x;         // 0..1023
    int b   = bid >> 5;           // 0..31
    int pr  = bid & 31;           // pair index 0..31
    int cA  = 2*pr, cB = 2*pr + 1;

    if (pr >= REPN/2) {           // ghost pair: two copies, retire
        #pragma unroll
        for (int it = 0; it < 2; ++it) {
            int c = cA + it;
            int cin = ghost_idx[c - REPN];
            const float4* s4 = (const float4*)(in + ((size_t)(b*Cn + cin))*HWn);
            float4* d4 = (float4*)(out + ((size_t)(b*Cn + c))*HWn);
            for (int i = tid; i < HWn/4; i += 128) d4[i] = s4[i];
        }
        return;
    }

    __shared__ unsigned planes[2][3*PLW];      // 2 tasks x 3 bf16 planes = 37632B
    __shared__ float swkA[63], swkB[63];
    __shared__ float red[2][6];
    __shared__ float sredA[6], sredB[6];

    block_weff(cA, tid,      w0, w1, Mh, Mv, Mid, swkA);
    block_weff(cB, tid - 64, w0, w1, Mh, Mv, Mid, swkB);
    __syncthreads();

    const float* chA = in + ((size_t)(b*Cn + rep_idx[cA]))*HWn;
    const float* chB = in + ((size_t)(b*Cn + rep_idx[cB]))*HWn;

    stats_and_arrive(chA, swkA, cA, tid, ws, red, planes[0]);
    stats_and_arrive(chB, swkB, cB, tid, ws, red, planes[1]);

    float* dstA = out + ((size_t)(b*Cn + cA))*HWn;
    float* dstB = out + ((size_t)(b*Cn + cB))*HWn;
    wait_and_finalize(chA, cA, tid, ws, sredA, planes[0], dstA);
    wait_and_finalize(chB, cB, tid, ws, sredB, planes[1], dstB);
}

// ------------------------------------- fallback: proven R6 2-kernel chain
__global__ void __launch_bounds__(128) k_pass1(const float* __restrict__ in,
        const float* __restrict__ w0, const float* __restrict__ w1,
        const int* __restrict__ Mh, const int* __restrict__ Mv,
        const int* __restrict__ Mid,
        const int* __restrict__ rep_idx, float* __restrict__ ws)
{
    int bid = blockIdx.x;
    int r = bid % REPN;
    int b = bid / REPN;
    int tid = threadIdx.x;

    __shared__ float swk[63];
    __shared__ float red[2][6];

    block_weff(r, tid, w0, w1, Mh, Mv, Mid, swk);
    __syncthreads();
    float wk[63];
    #pragma unroll
    for (int i = 0; i < 63; ++i) wk[i] = swk[i];

    const float* ch = in + ((size_t)(b*Cn + rep_idx[r]))*HWn;

    float s1=0.f,q1=0.f,s2=0.f,q2=0.f,s3=0.f,q3=0.f;
    conv_walk3(ch, wk, tid,
        [&](int h, int q, float* l1, float* l2, float* sm, float* res) {
            (void)h; (void)q; (void)res;
            #pragma unroll
            for (int p = 0; p < 4; ++p) {
                s1 += l1[p]; q1 += l1[p]*l1[p];
                s2 += l2[p]; q2 += l2[p]*l2[p];
                s3 += sm[p]; q3 += sm[p]*sm[p];
            }
        });

    float vals[6] = {s1,q1,s2,q2,s3,q3};
    int lane = tid & 63, wave = tid >> 6;
    #pragma unroll
    for (int x = 0; x < 6; ++x) {
        float y = vals[x];
        for (int o = 32; o; o >>= 1) y += __shfl_down(y, o, 64);
        if (lane == 0) red[wave][x] = y;
    }
    __syncthreads();
    if (tid < 6)
        ws[PART_OFF + (tid*REPN + r)*Bn + b] = red[0][tid] + red[1][tid];
}

__global__ void __launch_bounds__(128) k_pass2(const float* __restrict__ in,
        const float* __restrict__ w0, const float* __restrict__ w1,
        const int* __restrict__ Mh, const int* __restrict__ Mv,
        const int* __restrict__ Mid,
        const int* __restrict__ rep_idx, const int* __restrict__ ghost_idx,
        const float* __restrict__ ws, float* __restrict__ out)
{
    int bid = blockIdx.x;
    int c = bid & 63;
    int b = bid >> 6;
    int tid = threadIdx.x;

    if (c >= REPN) {
        int cin = ghost_idx[c - REPN];
        const float4* s4 = (const float4*)(in + ((size_t)(b*Cn + cin))*HWn);
        float4* d4 = (float4*)(out + ((size_t)(b*Cn + c))*HWn);
        for (int i = tid; i < HWn/4; i += 128) d4[i] = s4[i];
        return;
    }
    int r = c;

    __shared__ float swk[63];
    __shared__ float sred[6];

    block_weff(r, tid, w0, w1, Mh, Mv, Mid, swk);
    if (tid >= 64 && tid < 70) {
        int x = tid - 64;
        const float* pp = ws + PART_OFF + (x*REPN + r)*Bn;
        float s = 0.f;
        #pragma unroll
        for (int i = 0; i < Bn; ++i) s += pp[i];
        sred[x] = s;
    }
    __syncthreads();

    const float inv = 1.0f / NSTATf;
    float m1 = sred[0]*inv, v1 = sred[1]*inv - m1*m1;
    float m2 = sred[2]*inv, v2 = sred[3]*inv - m2*m2;
    float m3 = sred[4]*inv, v3 = sred[5]*inv - m3*m3;
    float r1 = rsqrtf(v1 + EPSf), r2 = rsqrtf(v2 + EPSf), r3 = rsqrtf(v3 + EPSf);
    float Kc = m1*r1 + m2*r2 + m3*r3;

    float cw0[9], cwA[9], cwB[9];
    #pragma unroll
    for (int ij = 0; ij < 9; ++ij) {
        cw0[ij] = r1*swk[ij]    + r2*swk[27+ij] + r3*swk[54+ij];
        cwA[ij] = r1*swk[9+ij]  + r2*swk[45+ij];
        cwB[ij] = r1*swk[18+ij] + r2*swk[36+ij];
    }

    const float* ch = in + ((size_t)(b*Cn + rep_idx[r]))*HWn;
    float* dst = out + ((size_t)(b*Cn + c))*HWn;
    conv_walk1(ch, cw0, cwA, cwB, Kc, tid, dst);
}

extern "C" void kernel_launch(void* const* d_in, const int* in_sizes, int n_in,
                              void* d_out, int out_size, void* d_ws, size_t ws_size,
                              hipStream_t stream) {
    const float* in   = (const float*)d_in[0];
    const float* w0   = (const float*)d_in[1];
    const float* w1   = (const float*)d_in[2];
    const int*   Mh   = (const int*)d_in[3];
    const int*   Mv   = (const int*)d_in[4];
    const int*   Mid  = (const int*)d_in[5];
    const int*   ghost= (const int*)d_in[6];
    const int*   rep  = (const int*)d_in[7];
    float* out  = (float*)d_out;
    float* ws   = (float*)d_ws;

    // Spin-safety gate: need 4 blocks/CU co-resident. LDS 38.2KB/block ->
    // exactly 4; VGPR<=256 ok. Capture-safe host-side query.
    int maxBlk = 0;
    hipError_t qerr = hipOccupancyMaxActiveBlocksPerMultiprocessor(
        &maxBlk, (const void*)k_fused, 128, 0);
    bool fused_ok = (qerr == hipSuccess) && (maxBlk >= 4);

    if (fused_ok) {
        hipError_t merr = hipMemsetAsync(ws, 0, INIT_BYTES, stream);
        if (merr == hipSuccess) {
            k_fused<<<GRID_FUSED, 128, 0, stream>>>(in, w0, w1, Mh, Mv, Mid,
                                                    rep, ghost, ws, out);
            return;
        }
    }
    // Fallback: proven R6 2-kernel chain
    k_pass1<<<REPN*Bn, 128, 0, stream>>>(in, w0, w1, Mh, Mv, Mid, rep, ws);
    k_pass2<<<Bn*Cn,   128, 0, stream>>>(in, w0, w1, Mh, Mv, Mid, rep, ghost, ws, out);
}